// Round 5
// baseline (260.145 us; speedup 1.0000x reference)
//
#include <hip/hip_runtime.h>
#include <hip/hip_fp16.h>

// ---- shape constants (N=100000 <= 131072 so src fits in 17 bits) ----
#define SB_SHIFT 8
#define SB_SIZE 256             // nodes per super-bucket (sortB parallelism: nsb=391)
#define MAXSB 512               // padded super-bucket array size
#define BIN_CHUNK 8192          // edges per chunk -> 391 blocks
#define BIN_THREADS 1024        // 16 waves/block -> ~12 waves/CU
#define SRC_BITS 17
#define SRC_MASK 0x1FFFF
#define NODES_PER_BLOCK 64      // mm1 tile
#define AGG_NODES 64            // nodes per agg block (256 threads, 4/node)

__global__ void zero_i_kernel(int* __restrict__ p, int total) {
  int i = blockIdx.x * blockDim.x + threadIdx.x;
  if (i < total) p[i] = 0;
}

// per-chunk histogram of col>>8 -> cntM[chunk][*], plus global totals bcnt
__global__ __launch_bounds__(BIN_THREADS) void histA_kernel(const int* __restrict__ col,
                                                            int* __restrict__ bcnt,
                                                            int* __restrict__ cntM,
                                                            int e, int nsb) {
  __shared__ int lc[MAXSB];
  int t = threadIdx.x;
  int chunk = blockIdx.x;
  int i0 = chunk * BIN_CHUNK;
  int i1 = min(i0 + BIN_CHUNK, e);
  if (t < MAXSB) lc[t] = 0;
  __syncthreads();
  for (int i = i0 + t; i < i1; i += BIN_THREADS)
    atomicAdd(&lc[col[i] >> SB_SHIFT], 1);
  __syncthreads();
  int* cm = cntM + (size_t)chunk * MAXSB;
  if (t < MAXSB) {
    int v = lc[t];
    cm[t] = v;
    if (t < nsb && v) atomicAdd(&bcnt[t], v);
  }
}

// exclusive scan over nsb (<=512) counts -> sbstart[0..nsb], bcur copy
__global__ __launch_bounds__(512) void scanA_kernel(const int* __restrict__ bcnt,
                                                    int* __restrict__ sbstart,
                                                    int* __restrict__ bcur, int nsb) {
  __shared__ int lds[512];
  int t = threadIdx.x;
  int v = (t < nsb) ? bcnt[t] : 0;
  lds[t] = v;
  __syncthreads();
  for (int off = 1; off < 512; off <<= 1) {
    int u = (t >= off) ? lds[t - off] : 0;
    __syncthreads();
    lds[t] += u;
    __syncthreads();
  }
  int excl = lds[t] - v;
  if (t < nsb) { sbstart[t] = excl; bcur[t] = excl; }
  if (t == 511) sbstart[nsb] = lds[511];
}

// pass A: LDS-staged radix partition into super-bucket groups.
// Scatter goes to LDS (cheap); global write is a linear sweep -> wave-coalesced
// full-line writes, bounded amplification regardless of run length.
// pairsA = src | colLow8<<17
__global__ __launch_bounds__(BIN_THREADS) void binA_kernel(const int* __restrict__ row,
                                                           const int* __restrict__ col,
                                                           const int* __restrict__ cntM,
                                                           int* __restrict__ bcur,
                                                           int* __restrict__ pairsA, int e) {
  __shared__ int stage[BIN_CHUNK];   // 32 KB staging
  __shared__ int cm[MAXSB];
  __shared__ int gbase[MAXSB];
  __shared__ int lb[MAXSB];          // exclusive local base (after scan)
  __shared__ int lcur[MAXSB];
  int t = threadIdx.x;
  int chunk = blockIdx.x;
  int i0 = chunk * BIN_CHUNK;
  int i1 = min(i0 + BIN_CHUNK, e);
  int csize = i1 - i0;
  const int* cmg = cntM + (size_t)chunk * MAXSB;
  if (t < MAXSB) {
    int c = cmg[t];
    cm[t] = c;
    gbase[t] = c ? atomicAdd(&bcur[t], c) : 0;
    lb[t] = c;
  }
  __syncthreads();
  // Hillis-Steele inclusive scan on lb[0..511]
  for (int off = 1; off < MAXSB; off <<= 1) {
    int u = (t < MAXSB && t >= off) ? lb[t - off] : 0;
    __syncthreads();
    if (t < MAXSB) lb[t] += u;
    __syncthreads();
  }
  if (t < MAXSB) {
    int ex = lb[t] - cm[t];   // exclusive base
    lb[t] = ex;
    lcur[t] = ex;
  }
  __syncthreads();
  // scatter into LDS staging, grouped by bucket
  for (int i = i0 + t; i < i1; i += BIN_THREADS) {
    int c = col[i];
    int b = c >> SB_SHIFT;
    int p = atomicAdd(&lcur[b], 1);
    stage[p] = row[i] | ((c & (SB_SIZE - 1)) << SRC_BITS);
  }
  __syncthreads();
  // linear flush: consecutive p -> consecutive dest within each bucket run
  for (int p = t; p < csize; p += BIN_THREADS) {
    int b = 0;
    #pragma unroll
    for (int step = 256; step > 0; step >>= 1) {
      int nb = b + step;
      if (nb < MAXSB && lb[nb] <= p) b = nb;
    }
    pairsA[gbase[b] + (p - lb[b])] = stage[p];
  }
}

// pass B: per super-bucket counting sort by local col -> node-sorted src array,
// node_start[] and dinv[] fall out of the histogram for free
__global__ __launch_bounds__(512) void sortB_kernel(const int* __restrict__ pairsA,
                                                    const int* __restrict__ sbstart,
                                                    int* __restrict__ pairs,
                                                    int* __restrict__ node_start,
                                                    float* __restrict__ dinv, int n) {
  __shared__ int cnt[SB_SIZE];
  __shared__ int base[SB_SIZE];
  __shared__ int cur[SB_SIZE];
  int b = blockIdx.x, t = threadIdx.x;
  int e0 = sbstart[b], e1 = sbstart[b + 1];
  if (t < SB_SIZE) cnt[t] = 0;
  __syncthreads();
  for (int i = e0 + t; i < e1; i += 512) atomicAdd(&cnt[pairsA[i] >> SRC_BITS], 1);
  __syncthreads();
  if (t < SB_SIZE) base[t] = cnt[t];
  __syncthreads();
  for (int off = 1; off < SB_SIZE; off <<= 1) {
    int u = (t < SB_SIZE && t >= off) ? base[t - off] : 0;
    __syncthreads();
    if (t < SB_SIZE) base[t] += u;
    __syncthreads();
  }
  if (t < SB_SIZE) {
    int excl = base[t] - cnt[t];
    cur[t] = excl;
    int node = (b << SB_SHIFT) + t;
    node_start[node] = e0 + excl;
    dinv[node] = rsqrtf((float)cnt[t] + 1.0f);
  }
  __syncthreads();
  for (int i = e0 + t; i < e1; i += 512) {
    int v = pairsA[i];
    int pos = e0 + atomicAdd(&cur[v >> SRC_BITS], 1);
    pairs[pos] = v & SRC_MASK;
  }
}

// s1 = fp16( (x @ W1) * dinv ) ; 32 B/row -> L2-resident table
__global__ __launch_bounds__(256) void mm1_kernel(const float* __restrict__ x,
                                                  const float* __restrict__ W1,
                                                  const float* __restrict__ dinv,
                                                  __half* __restrict__ s1, int n) {
  __shared__ float xs[NODES_PER_BLOCK][129];
  __shared__ float ws[128 * 16];
  int t = threadIdx.x;
  for (int i = t; i < 128 * 16; i += 256) ws[i] = W1[i];
  int base = blockIdx.x * NODES_PER_BLOCK;
  for (int i = t * 4; i < NODES_PER_BLOCK * 128; i += 256 * 4) {
    int nn = i >> 7, k = i & 127;
    if (base + nn < n) {
      float4 v = *(const float4*)(x + (size_t)(base + nn) * 128 + k);
      xs[nn][k] = v.x; xs[nn][k + 1] = v.y; xs[nn][k + 2] = v.z; xs[nn][k + 3] = v.w;
    }
  }
  __syncthreads();
  int nn = t >> 2;
  int j0 = (t & 3) * 4;
  float a0 = 0, a1 = 0, a2 = 0, a3 = 0;
  #pragma unroll 8
  for (int k = 0; k < 128; k++) {
    float xv = xs[nn][k];
    const float* wr = ws + k * 16 + j0;
    a0 += xv * wr[0]; a1 += xv * wr[1]; a2 += xv * wr[2]; a3 += xv * wr[3];
  }
  int node = base + nn;
  if (node < n) {
    float d = dinv[node];
    __half2 p0 = __floats2half2_rn(a0 * d, a1 * d);
    __half2 p1 = __floats2half2_rn(a2 * d, a3 * d);
    union { struct { __half2 a, b; } h; uint2 u; } pk;
    pk.h.a = p0; pk.h.b = p1;
    *(uint2*)(s1 + (size_t)node * 16 + j0) = pk.u;
  }
}

union H4 { float2 f2; __half2 h2[2]; };

__device__ __forceinline__ void acc_h4(const __half* __restrict__ tbl, int src, int q,
                                       float& a0, float& a1, float& a2, float& a3) {
  H4 w; w.f2 = *(const float2*)(tbl + (size_t)src * 16 + 4 * q);
  float2 l = __half22float2(w.h2[0]), h = __half22float2(w.h2[1]);
  a0 += l.x; a1 += l.y; a2 += h.x; a3 += h.y;
}

// dual-chain gather: split edge list in half, two independent 8-deep chains
// (16 outstanding loads/thread) -> covers L2 gather latency; merged at end.
__device__ __forceinline__ void gather_dual(const __half* __restrict__ tbl,
                                            const int* __restrict__ pairs,
                                            int j0, int en, int q,
                                            float& a0, float& a1, float& a2, float& a3) {
  float c0 = 0.f, c1 = 0.f, c2 = 0.f, c3 = 0.f;
  int mid = j0 + ((en - j0) >> 1);
  int jA = j0, jB = mid;
  for (; jA + 7 < mid && jB + 7 < en; jA += 8, jB += 8) {
    int pA0 = pairs[jA],     pA1 = pairs[jA + 1], pA2 = pairs[jA + 2], pA3 = pairs[jA + 3];
    int pA4 = pairs[jA + 4], pA5 = pairs[jA + 5], pA6 = pairs[jA + 6], pA7 = pairs[jA + 7];
    int pB0 = pairs[jB],     pB1 = pairs[jB + 1], pB2 = pairs[jB + 2], pB3 = pairs[jB + 3];
    int pB4 = pairs[jB + 4], pB5 = pairs[jB + 5], pB6 = pairs[jB + 6], pB7 = pairs[jB + 7];
    acc_h4(tbl, pA0, q, a0, a1, a2, a3); acc_h4(tbl, pB0, q, c0, c1, c2, c3);
    acc_h4(tbl, pA1, q, a0, a1, a2, a3); acc_h4(tbl, pB1, q, c0, c1, c2, c3);
    acc_h4(tbl, pA2, q, a0, a1, a2, a3); acc_h4(tbl, pB2, q, c0, c1, c2, c3);
    acc_h4(tbl, pA3, q, a0, a1, a2, a3); acc_h4(tbl, pB3, q, c0, c1, c2, c3);
    acc_h4(tbl, pA4, q, a0, a1, a2, a3); acc_h4(tbl, pB4, q, c0, c1, c2, c3);
    acc_h4(tbl, pA5, q, a0, a1, a2, a3); acc_h4(tbl, pB5, q, c0, c1, c2, c3);
    acc_h4(tbl, pA6, q, a0, a1, a2, a3); acc_h4(tbl, pB6, q, c0, c1, c2, c3);
    acc_h4(tbl, pA7, q, a0, a1, a2, a3); acc_h4(tbl, pB7, q, c0, c1, c2, c3);
  }
  for (; jA < mid; jA++) acc_h4(tbl, pairs[jA], q, a0, a1, a2, a3);
  for (; jB < en; jB++) acc_h4(tbl, pairs[jB], q, c0, c1, c2, c3);
  a0 += c0; a1 += c1; a2 += c2; a3 += c3;
}

// layer-1: dual-chain register aggregation + fused relu/bias/rescale
__global__ __launch_bounds__(256) void agg1_kernel(const int* __restrict__ pairs,
                                                   const int* __restrict__ node_start,
                                                   const __half* __restrict__ s1,
                                                   const float* __restrict__ dinv,
                                                   const float* __restrict__ b1,
                                                   __half* __restrict__ s2, int n) {
  __shared__ float lb1[16];
  int t = threadIdx.x;
  if (t < 16) lb1[t] = b1[t];
  __syncthreads();
  int node = blockIdx.x * AGG_NODES + (t >> 2);
  int q = t & 3;             // feature quad (4 halfs = 8 B)
  if (node >= n) return;     // no barriers after this point
  H4 u; u.f2 = *(const float2*)(s1 + (size_t)node * 16 + 4 * q);  // self loop
  float2 lo = __half22float2(u.h2[0]), hi = __half22float2(u.h2[1]);
  float a0 = lo.x, a1 = lo.y, a2 = hi.x, a3 = hi.y;
  gather_dual(s1, pairs, node_start[node], node_start[node + 1], q, a0, a1, a2, a3);
  float d = dinv[node];
  int f = 4 * q;
  a0 = fmaxf(fmaf(d, a0, lb1[f + 0]), 0.f) * d;
  a1 = fmaxf(fmaf(d, a1, lb1[f + 1]), 0.f) * d;
  a2 = fmaxf(fmaf(d, a2, lb1[f + 2]), 0.f) * d;
  a3 = fmaxf(fmaf(d, a3, lb1[f + 3]), 0.f) * d;
  H4 o; o.h2[0] = __floats2half2_rn(a0, a1); o.h2[1] = __floats2half2_rn(a2, a3);
  *(float2*)(s2 + (size_t)node * 16 + 4 * q) = o.f2;
}

// layer-2: dual-chain aggregation + fused 16->64 transform -> out (fp32)
__global__ __launch_bounds__(256) void agg2_kernel(const int* __restrict__ pairs,
                                                   const int* __restrict__ node_start,
                                                   const __half* __restrict__ s2,
                                                   const float* __restrict__ dinv,
                                                   const float* __restrict__ W2,
                                                   const float* __restrict__ b2,
                                                   float* __restrict__ out, int n) {
  __shared__ float tile[AGG_NODES * 16];   // pre-activation (exact ownership)
  __shared__ float w2s[16 * 64];
  __shared__ float b2s[64];
  int t = threadIdx.x;
  for (int i = t; i < 16 * 64; i += 256) w2s[i] = W2[i];
  if (t < 64) b2s[t] = b2[t];
  int node_l = t >> 2;
  int q = t & 3;
  int node = blockIdx.x * AGG_NODES + node_l;
  if (node < n) {
    H4 u; u.f2 = *(const float2*)(s2 + (size_t)node * 16 + 4 * q);  // self loop
    float2 lo = __half22float2(u.h2[0]), hi = __half22float2(u.h2[1]);
    float a0 = lo.x, a1 = lo.y, a2 = hi.x, a3 = hi.y;
    gather_dual(s2, pairs, node_start[node], node_start[node + 1], q, a0, a1, a2, a3);
    float d = dinv[node];
    float* tp = tile + node_l * 16 + 4 * q;
    tp[0] = a0 * d; tp[1] = a1 * d; tp[2] = a2 * d; tp[3] = a3 * d;
  }
  __syncthreads();
  int base = blockIdx.x * AGG_NODES;
  for (int idx = t; idx < AGG_NODES * 64; idx += 256) {
    int r = idx >> 6, jj = idx & 63;
    int onode = base + r;
    if (onode < n) {
      float o = b2s[jj];
      #pragma unroll
      for (int k = 0; k < 16; k++) o = fmaf(tile[r * 16 + k], w2s[k * 64 + jj], o);
      out[(size_t)onode * 64 + jj] = o;
    }
  }
}

extern "C" void kernel_launch(void* const* d_in, const int* in_sizes, int n_in,
                              void* d_out, int out_size, void* d_ws, size_t ws_size,
                              hipStream_t stream) {
  const float* x = (const float*)d_in[0];
  const int* ei = (const int*)d_in[1];   // int32 (JAX x64 disabled)
  const float* W1 = (const float*)d_in[2];
  const float* b1 = (const float*)d_in[3];
  const float* W2 = (const float*)d_in[4];
  const float* b2 = (const float*)d_in[5];
  float* out = (float*)d_out;

  int n = in_sizes[0] / 128;   // 100000
  int e = in_sizes[1] / 2;     // 3200000
  const int* row = ei;         // sources
  const int* col = ei + e;     // targets (aggregation index)
  int nsb = (n + SB_SIZE - 1) >> SB_SHIFT;           // 391 super-buckets
  int nchunks = (e + BIN_CHUNK - 1) / BIN_CHUNK;     // 391 chunks

  // workspace layout (ints; regions 16B-aligned). s1/s2 overlap dead pairsA.
  int* bcnt = (int*)d_ws;                     // 512
  int* sbstart = bcnt + 512;                  // 512+16
  int* bcur = sbstart + 528;                  // 512
  int* cntM = bcur + 512;                     // nchunks*MAXSB (<= 800*512 = 1.6 MB)
  int* pairsA = cntM + 800 * MAXSB;           // e  (12.8 MB; dead after sortB)
  int* pairs = pairsA + e;                    // e  (12.8 MB)
  int* node_start = pairs + e;                // 512*256+16
  float* dinv = (float*)(node_start + 512 * 256 + 16);  // 512*256
  __half* s1 = (__half*)pairsA;               // 16n halfs = 3.2 MB (inside pairsA)
  __half* s2 = s1 + (size_t)n * 16;           // 16n halfs = 3.2 MB (inside pairsA)

  // ---- node-sorted edge build (once; shared by both layers) ----
  zero_i_kernel<<<1, 512, 0, stream>>>(bcnt, 512);
  histA_kernel<<<nchunks, BIN_THREADS, 0, stream>>>(col, bcnt, cntM, e, nsb);
  scanA_kernel<<<1, 512, 0, stream>>>(bcnt, sbstart, bcur, nsb);
  binA_kernel<<<nchunks, BIN_THREADS, 0, stream>>>(row, col, cntM, bcur, pairsA, e);
  sortB_kernel<<<nsb, 512, 0, stream>>>(pairsA, sbstart, pairs, node_start, dinv, n);

  // ---- layer 1: transform (128->16) -> fp16 table, run-gather aggregate ----
  mm1_kernel<<<(n + NODES_PER_BLOCK - 1) / NODES_PER_BLOCK, 256, 0, stream>>>(x, W1, dinv, s1, n);
  agg1_kernel<<<(n + AGG_NODES - 1) / AGG_NODES, 256, 0, stream>>>(pairs, node_start, s1, dinv, b1, s2, n);

  // ---- layer 2: run-gather aggregate + fused 16->64 transform ----
  agg2_kernel<<<(n + AGG_NODES - 1) / AGG_NODES, 256, 0, stream>>>(pairs, node_start, s2, dinv, W2, b2, out, n);
}

// Round 6
// 253.931 us; speedup vs baseline: 1.0245x; 1.0245x over previous
//
#include <hip/hip_runtime.h>
#include <hip/hip_fp16.h>

// ---- shape constants (N=100000 <= 131072 so src fits in 17 bits) ----
#define SB_SHIFT 8
#define SB_SIZE 256             // nodes per super-bucket (sortB parallelism: nsb=391)
#define MAXSB 512               // padded super-bucket array size
#define BIN_CHUNK 8192          // edges per chunk -> 391 blocks
#define BIN_THREADS 1024        // 16 waves/block -> ~12 waves/CU
#define SRC_BITS 17
#define SRC_MASK 0x1FFFF
#define NODES_PER_BLOCK 64      // mm1 tile
#define AGG_NODES 16            // nodes per agg block (256 threads, 16/node)

__global__ void zero_i_kernel(int* __restrict__ p, int total) {
  int i = blockIdx.x * blockDim.x + threadIdx.x;
  if (i < total) p[i] = 0;
}

// per-chunk histogram of col>>8 -> cntM[chunk][*], plus global totals bcnt
__global__ __launch_bounds__(BIN_THREADS) void histA_kernel(const int* __restrict__ col,
                                                            int* __restrict__ bcnt,
                                                            int* __restrict__ cntM,
                                                            int e, int nsb) {
  __shared__ int lc[MAXSB];
  int t = threadIdx.x;
  int chunk = blockIdx.x;
  int i0 = chunk * BIN_CHUNK;
  int i1 = min(i0 + BIN_CHUNK, e);
  if (t < MAXSB) lc[t] = 0;
  __syncthreads();
  for (int i = i0 + t; i < i1; i += BIN_THREADS)
    atomicAdd(&lc[col[i] >> SB_SHIFT], 1);
  __syncthreads();
  int* cm = cntM + (size_t)chunk * MAXSB;
  if (t < MAXSB) {
    int v = lc[t];
    cm[t] = v;
    if (t < nsb && v) atomicAdd(&bcnt[t], v);
  }
}

// exclusive scan over nsb (<=512) counts -> sbstart[0..nsb], bcur copy
__global__ __launch_bounds__(512) void scanA_kernel(const int* __restrict__ bcnt,
                                                    int* __restrict__ sbstart,
                                                    int* __restrict__ bcur, int nsb) {
  __shared__ int lds[512];
  int t = threadIdx.x;
  int v = (t < nsb) ? bcnt[t] : 0;
  lds[t] = v;
  __syncthreads();
  for (int off = 1; off < 512; off <<= 1) {
    int u = (t >= off) ? lds[t - off] : 0;
    __syncthreads();
    lds[t] += u;
    __syncthreads();
  }
  int excl = lds[t] - v;
  if (t < nsb) { sbstart[t] = excl; bcur[t] = excl; }
  if (t == 511) sbstart[nsb] = lds[511];
}

// pass A: LDS-staged radix partition into super-bucket groups.
// Scatter goes to LDS (cheap); global write is a linear sweep -> wave-coalesced
// full-line writes, bounded amplification regardless of run length.
// pairsA = src | colLow8<<17
__global__ __launch_bounds__(BIN_THREADS) void binA_kernel(const int* __restrict__ row,
                                                           const int* __restrict__ col,
                                                           const int* __restrict__ cntM,
                                                           int* __restrict__ bcur,
                                                           int* __restrict__ pairsA, int e) {
  __shared__ int stage[BIN_CHUNK];   // 32 KB staging
  __shared__ int cm[MAXSB];
  __shared__ int gbase[MAXSB];
  __shared__ int lb[MAXSB];          // exclusive local base (after scan)
  __shared__ int lcur[MAXSB];
  int t = threadIdx.x;
  int chunk = blockIdx.x;
  int i0 = chunk * BIN_CHUNK;
  int i1 = min(i0 + BIN_CHUNK, e);
  int csize = i1 - i0;
  const int* cmg = cntM + (size_t)chunk * MAXSB;
  if (t < MAXSB) {
    int c = cmg[t];
    cm[t] = c;
    gbase[t] = c ? atomicAdd(&bcur[t], c) : 0;
    lb[t] = c;
  }
  __syncthreads();
  // Hillis-Steele inclusive scan on lb[0..511]
  for (int off = 1; off < MAXSB; off <<= 1) {
    int u = (t < MAXSB && t >= off) ? lb[t - off] : 0;
    __syncthreads();
    if (t < MAXSB) lb[t] += u;
    __syncthreads();
  }
  if (t < MAXSB) {
    int ex = lb[t] - cm[t];   // exclusive base
    lb[t] = ex;
    lcur[t] = ex;
  }
  __syncthreads();
  // scatter into LDS staging, grouped by bucket
  for (int i = i0 + t; i < i1; i += BIN_THREADS) {
    int c = col[i];
    int b = c >> SB_SHIFT;
    int p = atomicAdd(&lcur[b], 1);
    stage[p] = row[i] | ((c & (SB_SIZE - 1)) << SRC_BITS);
  }
  __syncthreads();
  // linear flush: consecutive p -> consecutive dest within each bucket run
  for (int p = t; p < csize; p += BIN_THREADS) {
    int b = 0;
    #pragma unroll
    for (int step = 256; step > 0; step >>= 1) {
      int nb = b + step;
      if (nb < MAXSB && lb[nb] <= p) b = nb;
    }
    pairsA[gbase[b] + (p - lb[b])] = stage[p];
  }
}

// pass B: per super-bucket counting sort by local col -> node-sorted src array,
// node_start[] and dinv[] fall out of the histogram for free
__global__ __launch_bounds__(512) void sortB_kernel(const int* __restrict__ pairsA,
                                                    const int* __restrict__ sbstart,
                                                    int* __restrict__ pairs,
                                                    int* __restrict__ node_start,
                                                    float* __restrict__ dinv, int n) {
  __shared__ int cnt[SB_SIZE];
  __shared__ int base[SB_SIZE];
  __shared__ int cur[SB_SIZE];
  int b = blockIdx.x, t = threadIdx.x;
  int e0 = sbstart[b], e1 = sbstart[b + 1];
  if (t < SB_SIZE) cnt[t] = 0;
  __syncthreads();
  for (int i = e0 + t; i < e1; i += 512) atomicAdd(&cnt[pairsA[i] >> SRC_BITS], 1);
  __syncthreads();
  if (t < SB_SIZE) base[t] = cnt[t];
  __syncthreads();
  for (int off = 1; off < SB_SIZE; off <<= 1) {
    int u = (t < SB_SIZE && t >= off) ? base[t - off] : 0;
    __syncthreads();
    if (t < SB_SIZE) base[t] += u;
    __syncthreads();
  }
  if (t < SB_SIZE) {
    int excl = base[t] - cnt[t];
    cur[t] = excl;
    int node = (b << SB_SHIFT) + t;
    node_start[node] = e0 + excl;
    dinv[node] = rsqrtf((float)cnt[t] + 1.0f);
  }
  __syncthreads();
  for (int i = e0 + t; i < e1; i += 512) {
    int v = pairsA[i];
    int pos = e0 + atomicAdd(&cur[v >> SRC_BITS], 1);
    pairs[pos] = v & SRC_MASK;
  }
}

// s1 = fp16( (x @ W1) * dinv ) ; 32 B/row -> L2-resident table
__global__ __launch_bounds__(256) void mm1_kernel(const float* __restrict__ x,
                                                  const float* __restrict__ W1,
                                                  const float* __restrict__ dinv,
                                                  __half* __restrict__ s1, int n) {
  __shared__ float xs[NODES_PER_BLOCK][129];
  __shared__ float ws[128 * 16];
  int t = threadIdx.x;
  for (int i = t; i < 128 * 16; i += 256) ws[i] = W1[i];
  int base = blockIdx.x * NODES_PER_BLOCK;
  for (int i = t * 4; i < NODES_PER_BLOCK * 128; i += 256 * 4) {
    int nn = i >> 7, k = i & 127;
    if (base + nn < n) {
      float4 v = *(const float4*)(x + (size_t)(base + nn) * 128 + k);
      xs[nn][k] = v.x; xs[nn][k + 1] = v.y; xs[nn][k + 2] = v.z; xs[nn][k + 3] = v.w;
    }
  }
  __syncthreads();
  int nn = t >> 2;
  int j0 = (t & 3) * 4;
  float a0 = 0, a1 = 0, a2 = 0, a3 = 0;
  #pragma unroll 8
  for (int k = 0; k < 128; k++) {
    float xv = xs[nn][k];
    const float* wr = ws + k * 16 + j0;
    a0 += xv * wr[0]; a1 += xv * wr[1]; a2 += xv * wr[2]; a3 += xv * wr[3];
  }
  int node = base + nn;
  if (node < n) {
    float d = dinv[node];
    __half2 p0 = __floats2half2_rn(a0 * d, a1 * d);
    __half2 p1 = __floats2half2_rn(a2 * d, a3 * d);
    union { struct { __half2 a, b; } h; uint2 u; } pk;
    pk.h.a = p0; pk.h.b = p1;
    *(uint2*)(s1 + (size_t)node * 16 + j0) = pk.u;
  }
}

union H4 { float2 f2; __half2 h2[2]; };

__device__ __forceinline__ void acc_h4(const __half* __restrict__ tbl, int src, int q,
                                       float& a0, float& a1, float& a2, float& a3) {
  H4 w; w.f2 = *(const float2*)(tbl + (size_t)src * 16 + 4 * q);
  float2 l = __half22float2(w.h2[0]), h = __half22float2(w.h2[1]);
  a0 += l.x; a1 += l.y; a2 += h.x; a3 += h.y;
}

// edge-lane-parallel gather: 4 edge-lanes per node each run one 8-deep chain
// over every 4th edge (deg~32 -> ~1 chunk/thread), merged by shfl_xor after.
__device__ __forceinline__ void gather_el(const __half* __restrict__ tbl,
                                          const int* __restrict__ pairs,
                                          int j0, int en, int el, int q,
                                          float& a0, float& a1, float& a2, float& a3) {
  int j = j0 + el;
  for (; j + 28 < en; j += 32) {   // 8 gathers/lane, 32 edges/group per iter
    int p0 = pairs[j],      p1 = pairs[j + 4],  p2 = pairs[j + 8],  p3 = pairs[j + 12];
    int p4 = pairs[j + 16], p5 = pairs[j + 20], p6 = pairs[j + 24], p7 = pairs[j + 28];
    acc_h4(tbl, p0, q, a0, a1, a2, a3); acc_h4(tbl, p1, q, a0, a1, a2, a3);
    acc_h4(tbl, p2, q, a0, a1, a2, a3); acc_h4(tbl, p3, q, a0, a1, a2, a3);
    acc_h4(tbl, p4, q, a0, a1, a2, a3); acc_h4(tbl, p5, q, a0, a1, a2, a3);
    acc_h4(tbl, p6, q, a0, a1, a2, a3); acc_h4(tbl, p7, q, a0, a1, a2, a3);
  }
  for (; j < en; j += 4) acc_h4(tbl, pairs[j], q, a0, a1, a2, a3);
  // merge the 4 edge-lanes (lanes differ in bits 2-3; within one wave)
  a0 += __shfl_xor(a0, 4); a1 += __shfl_xor(a1, 4);
  a2 += __shfl_xor(a2, 4); a3 += __shfl_xor(a3, 4);
  a0 += __shfl_xor(a0, 8); a1 += __shfl_xor(a1, 8);
  a2 += __shfl_xor(a2, 8); a3 += __shfl_xor(a3, 8);
}

// layer-1: 16 threads/node (4 edge-lanes x 4 feature-quads) + fused relu/bias
__global__ __launch_bounds__(256) void agg1_kernel(const int* __restrict__ pairs,
                                                   const int* __restrict__ node_start,
                                                   const __half* __restrict__ s1,
                                                   const float* __restrict__ dinv,
                                                   const float* __restrict__ b1,
                                                   __half* __restrict__ s2, int n) {
  __shared__ float lb1[16];
  int t = threadIdx.x;
  if (t < 16) lb1[t] = b1[t];
  __syncthreads();
  int node = blockIdx.x * AGG_NODES + (t >> 4);
  int el = (t >> 2) & 3;     // edge lane
  int q = t & 3;             // feature quad (4 halfs = 8 B)
  if (node >= n) return;     // uniform per 16-lane group
  float a0 = 0.f, a1 = 0.f, a2 = 0.f, a3 = 0.f;
  if (el == 0) {             // self loop counted once
    H4 u; u.f2 = *(const float2*)(s1 + (size_t)node * 16 + 4 * q);
    float2 lo = __half22float2(u.h2[0]), hi = __half22float2(u.h2[1]);
    a0 = lo.x; a1 = lo.y; a2 = hi.x; a3 = hi.y;
  }
  gather_el(s1, pairs, node_start[node], node_start[node + 1], el, q, a0, a1, a2, a3);
  if (el == 0) {
    float d = dinv[node];
    int f = 4 * q;
    a0 = fmaxf(fmaf(d, a0, lb1[f + 0]), 0.f) * d;
    a1 = fmaxf(fmaf(d, a1, lb1[f + 1]), 0.f) * d;
    a2 = fmaxf(fmaf(d, a2, lb1[f + 2]), 0.f) * d;
    a3 = fmaxf(fmaf(d, a3, lb1[f + 3]), 0.f) * d;
    H4 o; o.h2[0] = __floats2half2_rn(a0, a1); o.h2[1] = __floats2half2_rn(a2, a3);
    *(float2*)(s2 + (size_t)node * 16 + 4 * q) = o.f2;
  }
}

// layer-2: 16 threads/node aggregation + fused 16->64 transform -> out (fp32)
__global__ __launch_bounds__(256) void agg2_kernel(const int* __restrict__ pairs,
                                                   const int* __restrict__ node_start,
                                                   const __half* __restrict__ s2,
                                                   const float* __restrict__ dinv,
                                                   const float* __restrict__ W2,
                                                   const float* __restrict__ b2,
                                                   float* __restrict__ out, int n) {
  __shared__ float tile[AGG_NODES * 16];   // pre-activation (exact ownership)
  __shared__ float w2s[16 * 64];
  __shared__ float b2s[64];
  int t = threadIdx.x;
  for (int i = t; i < 16 * 64; i += 256) w2s[i] = W2[i];
  if (t < 64) b2s[t] = b2[t];
  int node_l = t >> 4;
  int el = (t >> 2) & 3;
  int q = t & 3;
  int node = blockIdx.x * AGG_NODES + node_l;
  if (node < n) {
    float a0 = 0.f, a1 = 0.f, a2 = 0.f, a3 = 0.f;
    if (el == 0) {
      H4 u; u.f2 = *(const float2*)(s2 + (size_t)node * 16 + 4 * q);
      float2 lo = __half22float2(u.h2[0]), hi = __half22float2(u.h2[1]);
      a0 = lo.x; a1 = lo.y; a2 = hi.x; a3 = hi.y;
    }
    gather_el(s2, pairs, node_start[node], node_start[node + 1], el, q, a0, a1, a2, a3);
    if (el == 0) {
      float d = dinv[node];
      float* tp = tile + node_l * 16 + 4 * q;
      tp[0] = a0 * d; tp[1] = a1 * d; tp[2] = a2 * d; tp[3] = a3 * d;
    }
  }
  __syncthreads();
  int base = blockIdx.x * AGG_NODES;
  for (int idx = t; idx < AGG_NODES * 64; idx += 256) {
    int r = idx >> 6, jj = idx & 63;
    int onode = base + r;
    if (onode < n) {
      float o = b2s[jj];
      #pragma unroll
      for (int k = 0; k < 16; k++) o = fmaf(tile[r * 16 + k], w2s[k * 64 + jj], o);
      out[(size_t)onode * 64 + jj] = o;
    }
  }
}

extern "C" void kernel_launch(void* const* d_in, const int* in_sizes, int n_in,
                              void* d_out, int out_size, void* d_ws, size_t ws_size,
                              hipStream_t stream) {
  const float* x = (const float*)d_in[0];
  const int* ei = (const int*)d_in[1];   // int32 (JAX x64 disabled)
  const float* W1 = (const float*)d_in[2];
  const float* b1 = (const float*)d_in[3];
  const float* W2 = (const float*)d_in[4];
  const float* b2 = (const float*)d_in[5];
  float* out = (float*)d_out;

  int n = in_sizes[0] / 128;   // 100000
  int e = in_sizes[1] / 2;     // 3200000
  const int* row = ei;         // sources
  const int* col = ei + e;     // targets (aggregation index)
  int nsb = (n + SB_SIZE - 1) >> SB_SHIFT;           // 391 super-buckets
  int nchunks = (e + BIN_CHUNK - 1) / BIN_CHUNK;     // 391 chunks

  // workspace layout (ints; regions 16B-aligned). s1/s2 overlap dead pairsA.
  int* bcnt = (int*)d_ws;                     // 512
  int* sbstart = bcnt + 512;                  // 512+16
  int* bcur = sbstart + 528;                  // 512
  int* cntM = bcur + 512;                     // nchunks*MAXSB (<= 800*512 = 1.6 MB)
  int* pairsA = cntM + 800 * MAXSB;           // e  (12.8 MB; dead after sortB)
  int* pairs = pairsA + e;                    // e  (12.8 MB)
  int* node_start = pairs + e;                // 512*256+16
  float* dinv = (float*)(node_start + 512 * 256 + 16);  // 512*256
  __half* s1 = (__half*)pairsA;               // 16n halfs = 3.2 MB (inside pairsA)
  __half* s2 = s1 + (size_t)n * 16;           // 16n halfs = 3.2 MB (inside pairsA)

  // ---- node-sorted edge build (once; shared by both layers) ----
  zero_i_kernel<<<1, 512, 0, stream>>>(bcnt, 512);
  histA_kernel<<<nchunks, BIN_THREADS, 0, stream>>>(col, bcnt, cntM, e, nsb);
  scanA_kernel<<<1, 512, 0, stream>>>(bcnt, sbstart, bcur, nsb);
  binA_kernel<<<nchunks, BIN_THREADS, 0, stream>>>(row, col, cntM, bcur, pairsA, e);
  sortB_kernel<<<nsb, 512, 0, stream>>>(pairsA, sbstart, pairs, node_start, dinv, n);

  // ---- layer 1: transform (128->16) -> fp16 table, edge-lane-parallel aggregate ----
  mm1_kernel<<<(n + NODES_PER_BLOCK - 1) / NODES_PER_BLOCK, 256, 0, stream>>>(x, W1, dinv, s1, n);
  agg1_kernel<<<(n + AGG_NODES - 1) / AGG_NODES, 256, 0, stream>>>(pairs, node_start, s1, dinv, b1, s2, n);

  // ---- layer 2: edge-lane-parallel aggregate + fused 16->64 transform ----
  agg2_kernel<<<(n + AGG_NODES - 1) / AGG_NODES, 256, 0, stream>>>(pairs, node_start, s2, dinv, W2, b2, out, n);
}

// Round 7
// 248.731 us; speedup vs baseline: 1.0459x; 1.0209x over previous
//
#include <hip/hip_runtime.h>
#include <hip/hip_fp16.h>

// ---- shape constants (N=100000 <= 131072 so src fits in 17 bits) ----
#define SB_SHIFT 8
#define SB_SIZE 256             // nodes per super-bucket (sortB parallelism: nsb=391)
#define MAXSB 512               // padded super-bucket array size
#define BIN_CHUNK 8192          // edges per chunk -> 391 blocks
#define BIN_THREADS 1024        // 16 waves/block -> ~12 waves/CU
#define SRC_BITS 17
#define SRC_MASK 0x1FFFF
#define NODES_PER_BLOCK 64      // mm1 tile
#define AGG_NODES 32            // nodes per agg block (256 threads, 8/node)

__global__ void zero_i_kernel(int* __restrict__ p, int total) {
  int i = blockIdx.x * blockDim.x + threadIdx.x;
  if (i < total) p[i] = 0;
}

// per-chunk histogram of col>>8 -> cntM[chunk][*], plus global totals bcnt
__global__ __launch_bounds__(BIN_THREADS) void histA_kernel(const int* __restrict__ col,
                                                            int* __restrict__ bcnt,
                                                            int* __restrict__ cntM,
                                                            int e, int nsb) {
  __shared__ int lc[MAXSB];
  int t = threadIdx.x;
  int chunk = blockIdx.x;
  int i0 = chunk * BIN_CHUNK;
  int i1 = min(i0 + BIN_CHUNK, e);
  if (t < MAXSB) lc[t] = 0;
  __syncthreads();
  for (int i = i0 + t; i < i1; i += BIN_THREADS)
    atomicAdd(&lc[col[i] >> SB_SHIFT], 1);
  __syncthreads();
  int* cm = cntM + (size_t)chunk * MAXSB;
  if (t < MAXSB) {
    int v = lc[t];
    cm[t] = v;
    if (t < nsb && v) atomicAdd(&bcnt[t], v);
  }
}

// exclusive scan over nsb (<=512) counts -> sbstart[0..nsb], bcur copy
__global__ __launch_bounds__(512) void scanA_kernel(const int* __restrict__ bcnt,
                                                    int* __restrict__ sbstart,
                                                    int* __restrict__ bcur, int nsb) {
  __shared__ int lds[512];
  int t = threadIdx.x;
  int v = (t < nsb) ? bcnt[t] : 0;
  lds[t] = v;
  __syncthreads();
  for (int off = 1; off < 512; off <<= 1) {
    int u = (t >= off) ? lds[t - off] : 0;
    __syncthreads();
    lds[t] += u;
    __syncthreads();
  }
  int excl = lds[t] - v;
  if (t < nsb) { sbstart[t] = excl; bcur[t] = excl; }
  if (t == 511) sbstart[nsb] = lds[511];
}

// pass A: LDS-staged radix partition into super-bucket groups.
// Scatter goes to LDS (cheap); global write is a linear sweep -> wave-coalesced
// full-line writes, bounded amplification regardless of run length.
// pairsA = src | colLow8<<17
__global__ __launch_bounds__(BIN_THREADS) void binA_kernel(const int* __restrict__ row,
                                                           const int* __restrict__ col,
                                                           const int* __restrict__ cntM,
                                                           int* __restrict__ bcur,
                                                           int* __restrict__ pairsA, int e) {
  __shared__ int stage[BIN_CHUNK];   // 32 KB staging
  __shared__ int cm[MAXSB];
  __shared__ int gbase[MAXSB];
  __shared__ int lb[MAXSB];          // exclusive local base (after scan)
  __shared__ int lcur[MAXSB];
  int t = threadIdx.x;
  int chunk = blockIdx.x;
  int i0 = chunk * BIN_CHUNK;
  int i1 = min(i0 + BIN_CHUNK, e);
  int csize = i1 - i0;
  const int* cmg = cntM + (size_t)chunk * MAXSB;
  if (t < MAXSB) {
    int c = cmg[t];
    cm[t] = c;
    gbase[t] = c ? atomicAdd(&bcur[t], c) : 0;
    lb[t] = c;
  }
  __syncthreads();
  // Hillis-Steele inclusive scan on lb[0..511]
  for (int off = 1; off < MAXSB; off <<= 1) {
    int u = (t < MAXSB && t >= off) ? lb[t - off] : 0;
    __syncthreads();
    if (t < MAXSB) lb[t] += u;
    __syncthreads();
  }
  if (t < MAXSB) {
    int ex = lb[t] - cm[t];   // exclusive base
    lb[t] = ex;
    lcur[t] = ex;
  }
  __syncthreads();
  // scatter into LDS staging, grouped by bucket
  for (int i = i0 + t; i < i1; i += BIN_THREADS) {
    int c = col[i];
    int b = c >> SB_SHIFT;
    int p = atomicAdd(&lcur[b], 1);
    stage[p] = row[i] | ((c & (SB_SIZE - 1)) << SRC_BITS);
  }
  __syncthreads();
  // linear flush: consecutive p -> consecutive dest within each bucket run
  for (int p = t; p < csize; p += BIN_THREADS) {
    int b = 0;
    #pragma unroll
    for (int step = 256; step > 0; step >>= 1) {
      int nb = b + step;
      if (nb < MAXSB && lb[nb] <= p) b = nb;
    }
    pairsA[gbase[b] + (p - lb[b])] = stage[p];
  }
}

// pass B: per super-bucket counting sort by local col -> node-sorted src array,
// node_start[] and dinv[] fall out of the histogram for free
__global__ __launch_bounds__(512) void sortB_kernel(const int* __restrict__ pairsA,
                                                    const int* __restrict__ sbstart,
                                                    int* __restrict__ pairs,
                                                    int* __restrict__ node_start,
                                                    float* __restrict__ dinv, int n) {
  __shared__ int cnt[SB_SIZE];
  __shared__ int base[SB_SIZE];
  __shared__ int cur[SB_SIZE];
  int b = blockIdx.x, t = threadIdx.x;
  int e0 = sbstart[b], e1 = sbstart[b + 1];
  if (t < SB_SIZE) cnt[t] = 0;
  __syncthreads();
  for (int i = e0 + t; i < e1; i += 512) atomicAdd(&cnt[pairsA[i] >> SRC_BITS], 1);
  __syncthreads();
  if (t < SB_SIZE) base[t] = cnt[t];
  __syncthreads();
  for (int off = 1; off < SB_SIZE; off <<= 1) {
    int u = (t < SB_SIZE && t >= off) ? base[t - off] : 0;
    __syncthreads();
    if (t < SB_SIZE) base[t] += u;
    __syncthreads();
  }
  if (t < SB_SIZE) {
    int excl = base[t] - cnt[t];
    cur[t] = excl;
    int node = (b << SB_SHIFT) + t;
    node_start[node] = e0 + excl;
    dinv[node] = rsqrtf((float)cnt[t] + 1.0f);
  }
  __syncthreads();
  for (int i = e0 + t; i < e1; i += 512) {
    int v = pairsA[i];
    int pos = e0 + atomicAdd(&cur[v >> SRC_BITS], 1);
    pairs[pos] = v & SRC_MASK;
  }
}

// s1 = fp16( (x @ W1) * dinv ) ; 32 B/row -> L2-resident table
__global__ __launch_bounds__(256) void mm1_kernel(const float* __restrict__ x,
                                                  const float* __restrict__ W1,
                                                  const float* __restrict__ dinv,
                                                  __half* __restrict__ s1, int n) {
  __shared__ float xs[NODES_PER_BLOCK][129];
  __shared__ float ws[128 * 16];
  int t = threadIdx.x;
  for (int i = t; i < 128 * 16; i += 256) ws[i] = W1[i];
  int base = blockIdx.x * NODES_PER_BLOCK;
  for (int i = t * 4; i < NODES_PER_BLOCK * 128; i += 256 * 4) {
    int nn = i >> 7, k = i & 127;
    if (base + nn < n) {
      float4 v = *(const float4*)(x + (size_t)(base + nn) * 128 + k);
      xs[nn][k] = v.x; xs[nn][k + 1] = v.y; xs[nn][k + 2] = v.z; xs[nn][k + 3] = v.w;
    }
  }
  __syncthreads();
  int nn = t >> 2;
  int j0 = (t & 3) * 4;
  float a0 = 0, a1 = 0, a2 = 0, a3 = 0;
  #pragma unroll 8
  for (int k = 0; k < 128; k++) {
    float xv = xs[nn][k];
    const float* wr = ws + k * 16 + j0;
    a0 += xv * wr[0]; a1 += xv * wr[1]; a2 += xv * wr[2]; a3 += xv * wr[3];
  }
  int node = base + nn;
  if (node < n) {
    float d = dinv[node];
    __half2 p0 = __floats2half2_rn(a0 * d, a1 * d);
    __half2 p1 = __floats2half2_rn(a2 * d, a3 * d);
    union { struct { __half2 a, b; } h; uint2 u; } pk;
    pk.h.a = p0; pk.h.b = p1;
    *(uint2*)(s1 + (size_t)node * 16 + j0) = pk.u;
  }
}

union H8 { float4 f4; __half2 h2[4]; };

// accumulate one 16 B half-row (8 halfs) into 8 fp32 accumulators
__device__ __forceinline__ void acc8(const __half* __restrict__ tbl, int src, int h,
                                     float* __restrict__ a) {
  H8 w; w.f4 = *(const float4*)(tbl + ((size_t)src << 4) + (h << 3));
  float2 f0 = __half22float2(w.h2[0]); a[0] += f0.x; a[1] += f0.y;
  float2 f1 = __half22float2(w.h2[1]); a[2] += f1.x; a[3] += f1.y;
  float2 f2 = __half22float2(w.h2[2]); a[4] += f2.x; a[5] += f2.y;
  float2 f3 = __half22float2(w.h2[3]); a[6] += f3.x; a[7] += f3.y;
}

// wide gather: 8 threads/node = 4 edge-lanes (el) x 2 half-rows (h).
// pairs read as aligned int4 (4 edges / lane-address), gathers are 16 B dwordx4.
// Head/tail of the unaligned segment handled by predication.
__device__ __forceinline__ void gather_w(const __half* __restrict__ tbl,
                                         const int* __restrict__ pairs,
                                         int s, int en, int el, int h,
                                         float* __restrict__ a) {
  int j = (s & ~3) + (el << 2);
  for (; j < en; j += 16) {
    int4 p = *(const int4*)(pairs + j);
    if (j     >= s && j     < en) acc8(tbl, p.x, h, a);
    if (j + 1 >= s && j + 1 < en) acc8(tbl, p.y, h, a);
    if (j + 2 >= s && j + 2 < en) acc8(tbl, p.z, h, a);
    if (j + 3 >= s && j + 3 < en) acc8(tbl, p.w, h, a);
  }
  // merge the 4 edge-lanes (xor masks 2,4 stay inside the 8-lane node group)
  #pragma unroll
  for (int k = 0; k < 8; k++) {
    a[k] += __shfl_xor(a[k], 2);
    a[k] += __shfl_xor(a[k], 4);
  }
}

// layer-1: wide-gather aggregation + fused relu/bias/rescale -> fp16 s2
__global__ __launch_bounds__(256) void agg1_kernel(const int* __restrict__ pairs,
                                                   const int* __restrict__ node_start,
                                                   const __half* __restrict__ s1,
                                                   const float* __restrict__ dinv,
                                                   const float* __restrict__ b1,
                                                   __half* __restrict__ s2, int n) {
  __shared__ float lb1[16];
  __shared__ int ns[AGG_NODES + 1];
  int t = threadIdx.x;
  int bn = blockIdx.x * AGG_NODES;
  if (t < 16) lb1[t] = b1[t];
  if (t <= AGG_NODES) ns[t] = node_start[min(bn + t, n)];
  __syncthreads();
  int node_l = t >> 3;
  int el = (t >> 1) & 3;
  int h = t & 1;
  int node = bn + node_l;
  if (node >= n) return;     // uniform per 8-lane group
  float a[8] = {0.f, 0.f, 0.f, 0.f, 0.f, 0.f, 0.f, 0.f};
  if (el == 0) acc8(s1, node, h, a);   // self loop counted once per h
  gather_w(s1, pairs, ns[node_l], ns[node_l + 1], el, h, a);
  if (el == 0) {
    float d = dinv[node];
    int f = h * 8;
    H8 o;
    #pragma unroll
    for (int k = 0; k < 4; k++) {
      float v0 = fmaxf(fmaf(d, a[2 * k],     lb1[f + 2 * k]),     0.f) * d;
      float v1 = fmaxf(fmaf(d, a[2 * k + 1], lb1[f + 2 * k + 1]), 0.f) * d;
      o.h2[k] = __floats2half2_rn(v0, v1);
    }
    *(float4*)(s2 + ((size_t)node << 4) + (h << 3)) = o.f4;   // 16 B store
  }
}

// layer-2: wide-gather aggregation + fused 16->64 transform -> out (fp32)
__global__ __launch_bounds__(256) void agg2_kernel(const int* __restrict__ pairs,
                                                   const int* __restrict__ node_start,
                                                   const __half* __restrict__ s2,
                                                   const float* __restrict__ dinv,
                                                   const float* __restrict__ W2,
                                                   const float* __restrict__ b2,
                                                   float* __restrict__ out, int n) {
  __shared__ float tile[AGG_NODES * 16];   // pre-activation (exact ownership)
  __shared__ float w2s[16 * 64];
  __shared__ float b2s[64];
  __shared__ int ns[AGG_NODES + 1];
  int t = threadIdx.x;
  int bn = blockIdx.x * AGG_NODES;
  for (int i = t; i < 16 * 64; i += 256) w2s[i] = W2[i];
  if (t < 64) b2s[t] = b2[t];
  if (t <= AGG_NODES) ns[t] = node_start[min(bn + t, n)];
  __syncthreads();
  int node_l = t >> 3;
  int el = (t >> 1) & 3;
  int h = t & 1;
  int node = bn + node_l;
  if (node < n) {
    float a[8] = {0.f, 0.f, 0.f, 0.f, 0.f, 0.f, 0.f, 0.f};
    if (el == 0) acc8(s2, node, h, a);   // self loop
    gather_w(s2, pairs, ns[node_l], ns[node_l + 1], el, h, a);
    if (el == 0) {
      float d = dinv[node];
      float* tp = tile + node_l * 16 + h * 8;
      #pragma unroll
      for (int k = 0; k < 8; k++) tp[k] = a[k] * d;
    }
  }
  __syncthreads();
  for (int idx = t; idx < AGG_NODES * 64; idx += 256) {
    int r = idx >> 6, jj = idx & 63;
    int onode = bn + r;
    if (onode < n) {
      float o = b2s[jj];
      #pragma unroll
      for (int k = 0; k < 16; k++) o = fmaf(tile[r * 16 + k], w2s[k * 64 + jj], o);
      out[(size_t)onode * 64 + jj] = o;
    }
  }
}

extern "C" void kernel_launch(void* const* d_in, const int* in_sizes, int n_in,
                              void* d_out, int out_size, void* d_ws, size_t ws_size,
                              hipStream_t stream) {
  const float* x = (const float*)d_in[0];
  const int* ei = (const int*)d_in[1];   // int32 (JAX x64 disabled)
  const float* W1 = (const float*)d_in[2];
  const float* b1 = (const float*)d_in[3];
  const float* W2 = (const float*)d_in[4];
  const float* b2 = (const float*)d_in[5];
  float* out = (float*)d_out;

  int n = in_sizes[0] / 128;   // 100000
  int e = in_sizes[1] / 2;     // 3200000
  const int* row = ei;         // sources
  const int* col = ei + e;     // targets (aggregation index)
  int nsb = (n + SB_SIZE - 1) >> SB_SHIFT;           // 391 super-buckets
  int nchunks = (e + BIN_CHUNK - 1) / BIN_CHUNK;     // 391 chunks

  // workspace layout (ints; regions 16B-aligned). s1/s2 overlap dead pairsA.
  int* bcnt = (int*)d_ws;                     // 512
  int* sbstart = bcnt + 512;                  // 512+16
  int* bcur = sbstart + 528;                  // 512
  int* cntM = bcur + 512;                     // nchunks*MAXSB (<= 800*512 = 1.6 MB)
  int* pairsA = cntM + 800 * MAXSB;           // e  (12.8 MB; dead after sortB)
  int* pairs = pairsA + e;                    // e  (12.8 MB)
  int* node_start = pairs + e;                // 512*256+16 (slack after pairs for int4 overshoot)
  float* dinv = (float*)(node_start + 512 * 256 + 16);  // 512*256
  __half* s1 = (__half*)pairsA;               // 16n halfs = 3.2 MB (inside pairsA)
  __half* s2 = s1 + (size_t)n * 16;           // 16n halfs = 3.2 MB (inside pairsA)

  // ---- node-sorted edge build (once; shared by both layers) ----
  zero_i_kernel<<<1, 512, 0, stream>>>(bcnt, 512);
  histA_kernel<<<nchunks, BIN_THREADS, 0, stream>>>(col, bcnt, cntM, e, nsb);
  scanA_kernel<<<1, 512, 0, stream>>>(bcnt, sbstart, bcur, nsb);
  binA_kernel<<<nchunks, BIN_THREADS, 0, stream>>>(row, col, cntM, bcur, pairsA, e);
  sortB_kernel<<<nsb, 512, 0, stream>>>(pairsA, sbstart, pairs, node_start, dinv, n);

  // ---- layer 1: transform (128->16) -> fp16 table, wide-gather aggregate ----
  mm1_kernel<<<(n + NODES_PER_BLOCK - 1) / NODES_PER_BLOCK, 256, 0, stream>>>(x, W1, dinv, s1, n);
  agg1_kernel<<<(n + AGG_NODES - 1) / AGG_NODES, 256, 0, stream>>>(pairs, node_start, s1, dinv, b1, s2, n);

  // ---- layer 2: wide-gather aggregate + fused 16->64 transform ----
  agg2_kernel<<<(n + AGG_NODES - 1) / AGG_NODES, 256, 0, stream>>>(pairs, node_start, s2, dinv, W2, b2, out, n);
}